// Round 6
// baseline (261.905 us; speedup 1.0000x reference)
//
#include <hip/hip_runtime.h>
#include <hip/hip_bf16.h>

// CrossAttention: out = softmax((X Wq)(KV Wk)^T / 8) (KV Wv) Wc
// B=2 S=T=2048 H=1024 nh=16 hd=64
// R6: 4-dispatch pipeline. gemm_qkv fuses fp32->bf16 cvt (fp32 A staging +
//     v_cvt_pk_bf16_f32 on fragment read) AND V-transpose (operand-swapped
//     MFMA for v-half blocks -> direct vt stores). Out-proj back to R4 config.

typedef unsigned short u16;
typedef __attribute__((ext_vector_type(4))) float float4v;
typedef __attribute__((ext_vector_type(8))) short short8;
typedef __attribute__((ext_vector_type(4))) float floatx4;

__device__ __forceinline__ u16 f2bf(float f) {
  unsigned u = __float_as_uint(f);
  u += 0x7fffu + ((u >> 16) & 1u);   // RNE
  return (u16)(u >> 16);
}

__device__ __forceinline__ float fast_exp2(float x) {
#if __has_builtin(__builtin_amdgcn_exp2f)
  return __builtin_amdgcn_exp2f(x);
#else
  return exp2f(x);
#endif
}

// pack two fp32 -> two bf16 in one u32 (low = a), RNE
__device__ __forceinline__ unsigned pack_bf2(float a, float b) {
#if __has_builtin(__builtin_amdgcn_cvt_pk_bf16_f32)
  auto r = __builtin_amdgcn_cvt_pk_bf16_f32(a, b);
  unsigned u;
  __builtin_memcpy(&u, &r, 4);
  return u;
#else
  unsigned ua = __float_as_uint(a) + 0x7fffu + ((__float_as_uint(a) >> 16) & 1u);
  unsigned ub = __float_as_uint(b) + 0x7fffu + ((__float_as_uint(b) >> 16) & 1u);
  return __builtin_amdgcn_perm(ub, ua, 0x07060302u);
#endif
}

__device__ __forceinline__ void store_out(float* p, float v) { *p = v; }
__device__ __forceinline__ void store_out(u16* p, float v) { *p = f2bf(v); }

__device__ __forceinline__ void gld16(const void* g, void* l) {
  __builtin_amdgcn_global_load_lds(
      (const __attribute__((address_space(1))) void*)g,
      (__attribute__((address_space(3))) void*)l, 16, 0, 0);
}

// ------------- merged transpose+cvt for Wq/Wkv/Wc: [1024][C] -> [C][1024] ----
__global__ void transpose_cvt3(const float* __restrict__ Wq,
                               const float* __restrict__ Wkv,
                               const float* __restrict__ Wc,
                               u16* __restrict__ Wqt, u16* __restrict__ Wkvt,
                               u16* __restrict__ Wct) {
  __shared__ float tile[32][33];
  const int z = blockIdx.z;
  const float* in = z == 0 ? Wq : (z == 1 ? Wkv : Wc);
  u16* out = z == 0 ? Wqt : (z == 1 ? Wkvt : Wct);
  const int C = (z == 1) ? 2048 : 1024;
  const int R = 1024;
  int bx = blockIdx.x * 32;
  if (bx >= C) return;
  int by = blockIdx.y * 32;
  int tx = threadIdx.x, ty = threadIdx.y;
#pragma unroll
  for (int i = 0; i < 32; i += 8)
    tile[ty + i][tx] = in[(size_t)(by + ty + i) * C + bx + tx];
  __syncthreads();
#pragma unroll
  for (int i = 0; i < 32; i += 8)
    out[(size_t)(bx + ty + i) * R + by + tx] = f2bf(tile[tx][ty + i]);
}

// ======= fused q/k/v projection: fp32 A staging + cvt, v-blocks swapped =====
// 128x128 tile, BK=32, dbuf, 256 threads (2x2 waves of 64x64).
// bx 0..7: q -> qp[4096][1024] (scale qscale)
// bx 8..15: k -> kp[4096][1024]
// bx 16..23: v -> vt[(b*1024+wc)][2048] via swapped MFMA (direct transpose)
__global__ __launch_bounds__(256) void gemm_qkv(const float* __restrict__ X,
                                                const float* __restrict__ KV,
                                                const u16* __restrict__ Wqt,
                                                const u16* __restrict__ Wkvt,
                                                u16* __restrict__ qp,
                                                u16* __restrict__ kp,
                                                u16* __restrict__ vt,
                                                float qscale) {
  __shared__ __align__(16) float Asf[2 * 4096];   // 32 KB: [buf][128r][32k] fp32
  __shared__ __align__(16) u16 Bs[2 * 4096];      // 16 KB: [buf][128n][32k] bf16
  const int t = threadIdx.x;
  const int w = t >> 6, l = t & 63;
  const int lane15 = l & 15, quad = l >> 4;
  const int wm = w >> 1, wn = w & 1;
  const int x3 = lane15 & 3, x7 = lane15 & 7;
  const int bm = blockIdx.y * 128;

  const int bx = blockIdx.x;
  const int mode = bx >> 3;                 // 0=q 1=k 2=v
  const float* A = (mode == 0) ? X : KV;
  const u16* Bt = (mode == 0) ? Wqt : Wkvt;
  const int bnw = (mode == 2) ? 1024 + (bx - 16) * 128 : (bx & 7) * 128;

  // A staging: 1024 16B-chunks/step; thread t handles chunks t+j*256 (j=0..3)
  const int arow = t >> 3;                              // + j*32
  const int acc_ = ((t & 7) ^ ((t >> 3) & 7)) << 2;     // swizzled col (floats)
  const float* ag[4];
#pragma unroll
  for (int j = 0; j < 4; ++j)
    ag[j] = A + (size_t)(bm + arow + j * 32) * 1024 + acc_;
  // B staging: 512 chunks/step; thread t handles chunks t+j*256 (j=0..1)
  const int brow = t >> 2;                              // + j*64
  const int bcc = ((t & 3) ^ ((t >> 2) & 3)) << 3;      // swizzled col (u16)
  const u16* bg[2];
#pragma unroll
  for (int j = 0; j < 2; ++j)
    bg[j] = Bt + (size_t)(bnw + brow + j * 64) * 1024 + bcc;

  // hoisted fragment offsets
  int afo0[4], afo1[4], bfo[4];
#pragma unroll
  for (int mi = 0; mi < 4; ++mi) {
    int row = wm * 64 + mi * 16 + lane15;
    afo0[mi] = row * 32 + (((quad * 2) ^ x7) << 2);
    afo1[mi] = row * 32 + (((quad * 2 + 1) ^ x7) << 2);
  }
#pragma unroll
  for (int ni = 0; ni < 4; ++ni)
    bfo[ni] = (wn * 64 + ni * 16 + lane15) * 32 + ((quad ^ x3) << 3);

  floatx4 acc[4][4] = {};
  const bool vswap = (mode == 2);

  auto stage = [&](int kt, int buf) {
#pragma unroll
    for (int j = 0; j < 4; ++j)
      gld16(ag[j] + kt, &Asf[buf * 4096 + (t + j * 256) * 4]);
#pragma unroll
    for (int j = 0; j < 2; ++j)
      gld16(bg[j] + kt, &Bs[buf * 4096 + (t + j * 256) * 8]);
  };
  auto compute = [&](int buf) {
    short8 af[4], bf[4];
#pragma unroll
    for (int mi = 0; mi < 4; ++mi) {
      float4v f0 = *(const float4v*)&Asf[buf * 4096 + afo0[mi]];
      float4v f1 = *(const float4v*)&Asf[buf * 4096 + afo1[mi]];
      union { short8 s; unsigned u[4]; } tmp;
      tmp.u[0] = pack_bf2(f0.x, f0.y);
      tmp.u[1] = pack_bf2(f0.z, f0.w);
      tmp.u[2] = pack_bf2(f1.x, f1.y);
      tmp.u[3] = pack_bf2(f1.z, f1.w);
      af[mi] = tmp.s;
    }
#pragma unroll
    for (int ni = 0; ni < 4; ++ni) bf[ni] = *(const short8*)&Bs[buf * 4096 + bfo[ni]];
    if (!vswap) {
#pragma unroll
      for (int mi = 0; mi < 4; ++mi)
#pragma unroll
        for (int ni = 0; ni < 4; ++ni)
          acc[mi][ni] = __builtin_amdgcn_mfma_f32_16x16x32_bf16(af[mi], bf[ni],
                                                                acc[mi][ni], 0, 0, 0);
    } else {
#pragma unroll
      for (int mi = 0; mi < 4; ++mi)
#pragma unroll
        for (int ni = 0; ni < 4; ++ni)
          acc[mi][ni] = __builtin_amdgcn_mfma_f32_16x16x32_bf16(bf[ni], af[mi],
                                                                acc[mi][ni], 0, 0, 0);
    }
  };

  stage(0, 0);
  __syncthreads();
  for (int kt = 0; kt < 1024; kt += 64) {
    if (kt + 32 < 1024) stage(kt + 32, 1);
    compute(0);
    __syncthreads();
    if (kt + 64 < 1024) stage(kt + 64, 0);
    compute(1);
    __syncthreads();
  }

  if (mode == 0) {
#pragma unroll
    for (int mi = 0; mi < 4; ++mi)
#pragma unroll
      for (int ni = 0; ni < 4; ++ni) {
        int col = bnw + wn * 64 + ni * 16 + lane15;
#pragma unroll
        for (int r = 0; r < 4; ++r) {
          int row = bm + wm * 64 + mi * 16 + quad * 4 + r;
          qp[(size_t)row * 1024 + col] = f2bf(acc[mi][ni][r] * qscale);
        }
      }
  } else if (mode == 1) {
#pragma unroll
    for (int mi = 0; mi < 4; ++mi)
#pragma unroll
      for (int ni = 0; ni < 4; ++ni) {
        int col = bnw + wn * 64 + ni * 16 + lane15;
#pragma unroll
        for (int r = 0; r < 4; ++r) {
          int row = bm + wm * 64 + mi * 16 + quad * 4 + r;
          kp[(size_t)row * 1024 + col] = f2bf(acc[mi][ni][r]);
        }
      }
  } else {
    // swapped: D[wc][t]; wc = weight-col - 1024, t local within batch
    const int b = bm >> 11;
    const int tbase = (bm & 2047) + wm * 64;
#pragma unroll
    for (int mi = 0; mi < 4; ++mi)
#pragma unroll
      for (int ni = 0; ni < 4; ++ni) {
        int tloc = tbase + mi * 16 + lane15;
#pragma unroll
        for (int r = 0; r < 4; ++r) {
          int wc = (bnw - 1024) + wn * 64 + ni * 16 + quad * 4 + r;
          vt[(size_t)(b * 1024 + wc) * 2048 + tloc] = f2bf(acc[mi][ni][r]);
        }
      }
  }
}

// ================ GEMM body (bf16 A): 128 x (NI*32) tile, BK=32, dbuf ========
template <typename OutT, int NI>
__device__ __forceinline__ void gemm_body(const u16* __restrict__ A,
                                          const u16* __restrict__ Bt,
                                          OutT* __restrict__ C,
                                          int N, int lda, int Klen, float scale,
                                          int bm, int bn,
                                          u16* As, u16* Bs) {
  const int t = threadIdx.x;
  const int w = t >> 6, l = t & 63;
  const int lane15 = l & 15, quad = l >> 4;
  const int wm = w >> 1, wn = w & 1;
  const int x3 = lane15 & 3;
  const int BSZ = NI * 1024;

  const int srow = t >> 2;
  const int scol = (((t & 3) ^ (srow & 3)) << 3);
  const u16* ag0 = A + (size_t)(bm + srow) * lda + scol;
  const u16* ag1 = ag0 + (size_t)64 * lda;
  const u16* bg0 = Bt + (size_t)(bn + srow) * lda + scol;
  const u16* bg1 = bg0 + (size_t)64 * lda;

  int afo[4], bfo[NI];
#pragma unroll
  for (int mi = 0; mi < 4; ++mi)
    afo[mi] = (wm * 64 + mi * 16 + lane15) * 32 + ((quad ^ x3) << 3);
#pragma unroll
  for (int ni = 0; ni < NI; ++ni)
    bfo[ni] = (wn * (NI * 16) + ni * 16 + lane15) * 32 + ((quad ^ x3) << 3);

  floatx4 acc[4][NI] = {};

  auto stage = [&](int kt, int ab, int bb) {
    gld16(ag0 + kt, &As[ab + t * 8]);
    gld16(ag1 + kt, &As[ab + 2048 + t * 8]);
    gld16(bg0 + kt, &Bs[bb + t * 8]);
    if (NI == 4) gld16(bg1 + kt, &Bs[bb + 2048 + t * 8]);
  };
  auto compute = [&](int ab, int bb) {
    short8 af[4], bf[NI];
#pragma unroll
    for (int mi = 0; mi < 4; ++mi) af[mi] = *(const short8*)&As[ab + afo[mi]];
#pragma unroll
    for (int ni = 0; ni < NI; ++ni) bf[ni] = *(const short8*)&Bs[bb + bfo[ni]];
#pragma unroll
    for (int mi = 0; mi < 4; ++mi)
#pragma unroll
      for (int ni = 0; ni < NI; ++ni)
        acc[mi][ni] = __builtin_amdgcn_mfma_f32_16x16x32_bf16(af[mi], bf[ni],
                                                              acc[mi][ni], 0, 0, 0);
  };

  stage(0, 0, 0);
  __syncthreads();
  for (int kt = 0; kt < Klen; kt += 64) {
    if (kt + 32 < Klen) stage(kt + 32, 4096, BSZ);
    compute(0, 0);
    __syncthreads();
    if (kt + 64 < Klen) stage(kt + 64, 0, 0);
    compute(4096, BSZ);
    __syncthreads();
  }

#pragma unroll
  for (int mi = 0; mi < 4; ++mi)
#pragma unroll
    for (int ni = 0; ni < NI; ++ni) {
      int col = bn + wn * (NI * 16) + ni * 16 + lane15;
#pragma unroll
      for (int r = 0; r < 4; ++r) {
        int row = bm + wm * 64 + mi * 16 + quad * 4 + r;
        store_out(&C[(size_t)row * N + col], acc[mi][ni][r] * scale);
      }
    }
}

// output projection, 128x64 tiles (512 blocks, 2/CU), fp32 out
__global__ __launch_bounds__(256) void gemm_out(const u16* __restrict__ A,
                                                const u16* __restrict__ Bt,
                                                float* __restrict__ C) {
  __shared__ __align__(16) u16 As[2 * 4096];
  __shared__ __align__(16) u16 Bs[2 * 2048];
  gemm_body<float, 2>(A, Bt, C, 1024, 1024, 1024, 1.0f, blockIdx.y * 128,
                      blockIdx.x * 64, As, Bs);
}

// ---------------- flash attention (S^T layout, BM=128, 8 waves, dbuf x2) ----
// Q pre-scaled by 0.125*log2e; p = exp2(s); l via ones-MFMA (C-layout).
// K from kp[4096][1024], V from vt[(b*1024+wc)][2048].
__global__ __launch_bounds__(512) void attn_kern(const u16* __restrict__ Q,
                                                 const u16* __restrict__ KP,
                                                 const u16* __restrict__ VT,
                                                 u16* __restrict__ Y) {
  __shared__ __align__(16) u16 Ks[2 * 4096];    // [buf][t'][d], chunk^=(t'&7)
  __shared__ __align__(16) u16 VTs[2 * 4096];   // [buf][d][t'], chunk^=(d&7)
  __shared__ __align__(16) u16 Ps[8192];        // [m 0..127][t'], chunk^=(m&7)
  const int t = threadIdx.x, w = t >> 6, l = t & 63;
  const int lane15 = l & 15, quad = l >> 4;
  const int bh = blockIdx.y, b = bh >> 4, h = bh & 15;
  const int qrow0 = b * 2048 + blockIdx.x * 128;
  const int xm = lane15 & 7;

  short8 qf[2];
#pragma unroll
  for (int ks = 0; ks < 2; ++ks)
    qf[ks] = *(const short8*)&Q[(size_t)(qrow0 + w * 16 + lane15) * 1024 +
                                h * 64 + ks * 32 + quad * 8];

  const short8 vones = {0x3F80, 0x3F80, 0x3F80, 0x3F80,
                        0x3F80, 0x3F80, 0x3F80, 0x3F80};

  floatx4 yacc[4] = {};
  floatx4 lacc = {};

  const int srow = t >> 3;                          // 0..63
  const int scol = (((t & 7) ^ (srow & 7)) << 3);
  const u16* kg = KP + (size_t)(b * 2048 + srow) * 1024 + h * 64 + scol;
  const u16* vg = VT + (size_t)(bh * 64 + srow) * 2048 + scol;

  const int prow = (w * 16 + lane15) * 64;
  int kfo[2][4], vfo[2][4], pwo[4], pro[2];
#pragma unroll
  for (int ks = 0; ks < 2; ++ks)
#pragma unroll
    for (int ti = 0; ti < 4; ++ti)
      kfo[ks][ti] = (ti * 16 + lane15) * 64 + (((ks * 4 + quad) ^ xm) << 3);
#pragma unroll
  for (int ts = 0; ts < 2; ++ts) {
#pragma unroll
    for (int ni = 0; ni < 4; ++ni)
      vfo[ts][ni] = (ni * 16 + lane15) * 64 + (((ts * 4 + quad) ^ xm) << 3);
    pro[ts] = prow + (((ts * 4 + quad) ^ xm) << 3);
  }
#pragma unroll
  for (int ti = 0; ti < 4; ++ti)
    pwo[ti] = prow + (((ti * 2 + (quad >> 1)) ^ xm) << 3) + ((quad & 1) << 2);

  auto stage = [&](int t0n, int buf) {
    gld16(kg + (size_t)t0n * 1024, &Ks[buf + t * 8]);
    gld16(vg + t0n, &VTs[buf + t * 8]);
  };
  auto compute = [&](int buf) {
    floatx4 sacc[4] = {};
#pragma unroll
    for (int ks = 0; ks < 2; ++ks)
#pragma unroll
      for (int ti = 0; ti < 4; ++ti) {
        short8 kf = *(const short8*)&Ks[buf + kfo[ks][ti]];
        sacc[ti] = __builtin_amdgcn_mfma_f32_16x16x32_bf16(kf, qf[ks], sacc[ti], 0, 0, 0);
      }
#pragma unroll
    for (int ti = 0; ti < 4; ++ti) {
      float p0 = fast_exp2(sacc[ti][0]);
      float p1 = fast_exp2(sacc[ti][1]);
      float p2 = fast_exp2(sacc[ti][2]);
      float p3 = fast_exp2(sacc[ti][3]);
      uint2 pk;
      pk.x = pack_bf2(p0, p1);
      pk.y = pack_bf2(p2, p3);
      *(uint2*)&Ps[pwo[ti]] = pk;
    }
#pragma unroll
    for (int ts = 0; ts < 2; ++ts) {
      short8 pf = *(const short8*)&Ps[pro[ts]];
      lacc = __builtin_amdgcn_mfma_f32_16x16x32_bf16(pf, vones, lacc, 0, 0, 0);
#pragma unroll
      for (int ni = 0; ni < 4; ++ni) {
        short8 vf = *(const short8*)&VTs[buf + vfo[ts][ni]];
        yacc[ni] = __builtin_amdgcn_mfma_f32_16x16x32_bf16(pf, vf, yacc[ni], 0, 0, 0);
      }
    }
  };

  stage(0, 0);
  __syncthreads();
  for (int t0 = 0; t0 < 2048; t0 += 128) {
    if (t0 + 64 < 2048) stage(t0 + 64, 4096);
    compute(0);
    __syncthreads();
    if (t0 + 128 < 2048) stage(t0 + 128, 0);
    compute(4096);
    __syncthreads();
  }

#pragma unroll
  for (int r = 0; r < 4; ++r) {
    float linv = 1.0f / lacc[r];
    int row = qrow0 + w * 16 + quad * 4 + r;
#pragma unroll
    for (int ni = 0; ni < 4; ++ni)
      Y[(size_t)row * 1024 + h * 64 + ni * 16 + lane15] = f2bf(yacc[ni][r] * linv);
  }
}

// ---------------- launch ----------------
extern "C" void kernel_launch(void* const* d_in, const int* in_sizes, int n_in,
                              void* d_out, int out_size, void* d_ws, size_t ws_size,
                              hipStream_t stream) {
  const float* query = (const float*)d_in[0];      // [2,2048,1024]
  const float* key_value = (const float*)d_in[1];  // [2,2048,1024]
  const float* Wq = (const float*)d_in[2];         // [1024,1024]
  const float* Wkv = (const float*)d_in[3];        // [1024,2048]
  const float* Wc = (const float*)d_in[4];         // [1024,1024]
  float* out = (float*)d_out;                      // [2,2048,1024] fp32

  const size_t MB = 1024 * 1024;
  char* ws = (char*)d_ws;
  u16* Wqt  = (u16*)(ws + 0 * MB);    // 2 MB
  u16* Wkvt = (u16*)(ws + 2 * MB);    // 4 MB
  u16* Wct  = (u16*)(ws + 6 * MB);    // 2 MB
  u16* qp   = (u16*)(ws + 8 * MB);    // 8 MB   q = X Wq * 0.125*log2e
  u16* kp   = (u16*)(ws + 16 * MB);   // 8 MB   k [4096][1024]
  u16* vt   = (u16*)(ws + 24 * MB);   // 8 MB   v transposed [b*1024+wc][2048]
  u16* y    = (u16*)(ws + 32 * MB);   // 8 MB   attention output

  transpose_cvt3<<<dim3(64, 32, 3), dim3(32, 8), 0, stream>>>(Wq, Wkv, Wc,
                                                              Wqt, Wkvt, Wct);
  const float qscale = 0.125f * 1.4426950408889634f;  // 1/sqrt(hd) * log2(e)
  gemm_qkv<<<dim3(24, 32), dim3(256), 0, stream>>>(query, key_value, Wqt, Wkvt,
                                                   qp, kp, vt, qscale);
  attn_kern<<<dim3(16, 32), dim3(512), 0, stream>>>(qp, kp, vt, y);
  gemm_out<<<dim3(16, 32), dim3(256), 0, stream>>>(y, Wct, out);
}

// Round 7
// 224.788 us; speedup vs baseline: 1.1651x; 1.1651x over previous
//
#include <hip/hip_runtime.h>
#include <hip/hip_bf16.h>

// CrossAttention: out = softmax((X Wq)(KV Wk)^T / 8) (KV Wv) Wc
// B=2 S=T=2048 H=1024 nh=16 hd=64
// R7: bf16-staged gemm_qkv (R5) + V-swap epilogue (R6) -> no transpose_v;
//     gemm_out BK=64 (16 MFMA/barrier); 5-dispatch pipeline.

typedef unsigned short u16;
typedef __attribute__((ext_vector_type(4))) float float4v;
typedef __attribute__((ext_vector_type(4))) unsigned short u16x4;
typedef __attribute__((ext_vector_type(8))) short short8;
typedef __attribute__((ext_vector_type(4))) float floatx4;

__device__ __forceinline__ u16 f2bf(float f) {
  unsigned u = __float_as_uint(f);
  u += 0x7fffu + ((u >> 16) & 1u);   // RNE
  return (u16)(u >> 16);
}

__device__ __forceinline__ float fast_exp2(float x) {
#if __has_builtin(__builtin_amdgcn_exp2f)
  return __builtin_amdgcn_exp2f(x);
#else
  return exp2f(x);
#endif
}

// pack two fp32 -> two bf16 in one u32 (low = a), RNE
__device__ __forceinline__ unsigned pack_bf2(float a, float b) {
#if __has_builtin(__builtin_amdgcn_cvt_pk_bf16_f32)
  auto r = __builtin_amdgcn_cvt_pk_bf16_f32(a, b);
  unsigned u;
  __builtin_memcpy(&u, &r, 4);
  return u;
#else
  unsigned ua = __float_as_uint(a) + 0x7fffu + ((__float_as_uint(a) >> 16) & 1u);
  unsigned ub = __float_as_uint(b) + 0x7fffu + ((__float_as_uint(b) >> 16) & 1u);
  return __builtin_amdgcn_perm(ub, ua, 0x07060302u);
#endif
}

__device__ __forceinline__ void gld16(const void* g, void* l) {
  __builtin_amdgcn_global_load_lds(
      (const __attribute__((address_space(1))) void*)g,
      (__attribute__((address_space(3))) void*)l, 16, 0, 0);
}

// ---------------- elementwise fp32 -> bf16 (two tensors in one launch) ------
__global__ void cvt_bf16_2(const float* __restrict__ a, const float* __restrict__ b,
                           u16* __restrict__ oa, u16* __restrict__ ob, int n4) {
  int i = blockIdx.x * blockDim.x + threadIdx.x;
  if (i >= n4) return;
  const float* src = blockIdx.y ? b : a;
  u16* dst = blockIdx.y ? ob : oa;
  float4v v = ((const float4v*)src)[i];
  u16x4 o;
  o.x = f2bf(v.x); o.y = f2bf(v.y); o.z = f2bf(v.z); o.w = f2bf(v.w);
  ((u16x4*)dst)[i] = o;
}

// ------------- merged transpose+cvt for Wq/Wkv/Wc: [1024][C] -> [C][1024] ----
__global__ void transpose_cvt3(const float* __restrict__ Wq,
                               const float* __restrict__ Wkv,
                               const float* __restrict__ Wc,
                               u16* __restrict__ Wqt, u16* __restrict__ Wkvt,
                               u16* __restrict__ Wct) {
  __shared__ float tile[32][33];
  const int z = blockIdx.z;
  const float* in = z == 0 ? Wq : (z == 1 ? Wkv : Wc);
  u16* out = z == 0 ? Wqt : (z == 1 ? Wkvt : Wct);
  const int C = (z == 1) ? 2048 : 1024;
  const int R = 1024;
  int bx = blockIdx.x * 32;
  if (bx >= C) return;
  int by = blockIdx.y * 32;
  int tx = threadIdx.x, ty = threadIdx.y;
#pragma unroll
  for (int i = 0; i < 32; i += 8)
    tile[ty + i][tx] = in[(size_t)(by + ty + i) * C + bx + tx];
  __syncthreads();
#pragma unroll
  for (int i = 0; i < 32; i += 8)
    out[(size_t)(bx + ty + i) * R + by + tx] = f2bf(tile[tx][ty + i]);
}

// ======= fused q/k/v projection (bf16 A), 128x128, BK=32, dbuf ==============
// bx 0..7: q -> qp[4096][1024] (scale qscale); bx 8..15: k -> kp[4096][1024];
// bx 16..23: v via swapped MFMA -> vt[(b*1024+wc)][2048] (direct transpose).
__global__ __launch_bounds__(256) void gemm_qkv(const u16* __restrict__ qin,
                                                const u16* __restrict__ kvin,
                                                const u16* __restrict__ Wqt,
                                                const u16* __restrict__ Wkvt,
                                                u16* __restrict__ qp,
                                                u16* __restrict__ kp,
                                                u16* __restrict__ vt,
                                                float qscale) {
  __shared__ __align__(16) u16 As[2 * 4096];
  __shared__ __align__(16) u16 Bs[2 * 4096];
  const int t = threadIdx.x;
  const int w = t >> 6, l = t & 63;
  const int lane15 = l & 15, quad = l >> 4;
  const int wm = w >> 1, wn = w & 1;
  const int x3 = lane15 & 3;
  const int bm = blockIdx.y * 128;

  const int bx = blockIdx.x;
  const int mode = bx >> 3;                 // 0=q 1=k 2=v
  const u16* A = (mode == 0) ? qin : kvin;
  const u16* Bt = (mode == 0) ? Wqt : Wkvt;
  const int bn = (mode == 2) ? 1024 + (bx - 16) * 128 : (bx & 7) * 128;

  const int srow = t >> 2;                            // 0..63
  const int scol = (((t & 3) ^ (srow & 3)) << 3);
  const u16* ag0 = A + (size_t)(bm + srow) * 1024 + scol;
  const u16* ag1 = ag0 + (size_t)64 * 1024;
  const u16* bg0 = Bt + (size_t)(bn + srow) * 1024 + scol;
  const u16* bg1 = bg0 + (size_t)64 * 1024;

  int afo[4], bfo[4];
#pragma unroll
  for (int mi = 0; mi < 4; ++mi)
    afo[mi] = (wm * 64 + mi * 16 + lane15) * 32 + ((quad ^ x3) << 3);
#pragma unroll
  for (int ni = 0; ni < 4; ++ni)
    bfo[ni] = (wn * 64 + ni * 16 + lane15) * 32 + ((quad ^ x3) << 3);

  floatx4 acc[4][4] = {};
  const bool vswap = (mode == 2);

  auto stage = [&](int kt, int buf) {
    gld16(ag0 + kt, &As[buf * 4096 + t * 8]);
    gld16(ag1 + kt, &As[buf * 4096 + 2048 + t * 8]);
    gld16(bg0 + kt, &Bs[buf * 4096 + t * 8]);
    gld16(bg1 + kt, &Bs[buf * 4096 + 2048 + t * 8]);
  };
  auto compute = [&](int buf) {
    short8 af[4], bf[4];
#pragma unroll
    for (int mi = 0; mi < 4; ++mi) af[mi] = *(const short8*)&As[buf * 4096 + afo[mi]];
#pragma unroll
    for (int ni = 0; ni < 4; ++ni) bf[ni] = *(const short8*)&Bs[buf * 4096 + bfo[ni]];
    if (!vswap) {
#pragma unroll
      for (int mi = 0; mi < 4; ++mi)
#pragma unroll
        for (int ni = 0; ni < 4; ++ni)
          acc[mi][ni] = __builtin_amdgcn_mfma_f32_16x16x32_bf16(af[mi], bf[ni],
                                                                acc[mi][ni], 0, 0, 0);
    } else {
#pragma unroll
      for (int mi = 0; mi < 4; ++mi)
#pragma unroll
        for (int ni = 0; ni < 4; ++ni)
          acc[mi][ni] = __builtin_amdgcn_mfma_f32_16x16x32_bf16(bf[ni], af[mi],
                                                                acc[mi][ni], 0, 0, 0);
    }
  };

  stage(0, 0);
  __syncthreads();
  for (int kt = 0; kt < 1024; kt += 64) {
    if (kt + 32 < 1024) stage(kt + 32, 1);
    compute(0);
    __syncthreads();
    if (kt + 64 < 1024) stage(kt + 64, 0);
    compute(1);
    __syncthreads();
  }

  if (mode == 0) {
#pragma unroll
    for (int mi = 0; mi < 4; ++mi)
#pragma unroll
      for (int ni = 0; ni < 4; ++ni) {
        int col = bn + wn * 64 + ni * 16 + lane15;
#pragma unroll
        for (int r = 0; r < 4; ++r) {
          int row = bm + wm * 64 + mi * 16 + quad * 4 + r;
          qp[(size_t)row * 1024 + col] = f2bf(acc[mi][ni][r] * qscale);
        }
      }
  } else if (mode == 1) {
#pragma unroll
    for (int mi = 0; mi < 4; ++mi)
#pragma unroll
      for (int ni = 0; ni < 4; ++ni) {
        int col = bn + wn * 64 + ni * 16 + lane15;
#pragma unroll
        for (int r = 0; r < 4; ++r) {
          int row = bm + wm * 64 + mi * 16 + quad * 4 + r;
          kp[(size_t)row * 1024 + col] = f2bf(acc[mi][ni][r]);
        }
      }
  } else {
    // swapped: D rows = weight col (wc), D cols = activation row (t)
    const int b = bm >> 11;
    const int tbase = (bm & 2047) + wm * 64;
#pragma unroll
    for (int mi = 0; mi < 4; ++mi)
#pragma unroll
      for (int ni = 0; ni < 4; ++ni) {
        int tloc = tbase + mi * 16 + lane15;
#pragma unroll
        for (int r = 0; r < 4; ++r) {
          int wc = (bn - 1024) + wn * 64 + ni * 16 + quad * 4 + r;
          vt[(size_t)(b * 1024 + wc) * 2048 + tloc] = f2bf(acc[mi][ni][r]);
        }
      }
  }
}

// ============== output projection: 128x64 tile, BK=64, dbuf =================
// 16 MFMA + 6 gld16 per barrier; LDS 48 KB; grid (16,32)=512 blocks.
__global__ __launch_bounds__(256) void gemm_out(const u16* __restrict__ A,
                                                const u16* __restrict__ Bt,
                                                float* __restrict__ C) {
  __shared__ __align__(16) u16 As[2 * 8192];   // [buf][128][64]
  __shared__ __align__(16) u16 Bs[2 * 4096];   // [buf][64][64]
  const int t = threadIdx.x;
  const int w = t >> 6, l = t & 63;
  const int lane15 = l & 15, quad = l >> 4;
  const int wm = w >> 1, wn = w & 1;
  const int xm = lane15 & 7;
  const int bm = blockIdx.y * 128, bn = blockIdx.x * 64;

  const int arow = t >> 3;                          // 0..31 (+j*32)
  const int scol = (((t & 7) ^ ((t >> 3) & 7)) << 3);
  const u16* ag[4];
#pragma unroll
  for (int j = 0; j < 4; ++j)
    ag[j] = A + (size_t)(bm + arow + j * 32) * 1024 + scol;
  const u16* bg[2];
#pragma unroll
  for (int j = 0; j < 2; ++j)
    bg[j] = Bt + (size_t)(bn + arow + j * 32) * 1024 + scol;

  int afo[2][4], bfo[2][2];
#pragma unroll
  for (int ks = 0; ks < 2; ++ks) {
#pragma unroll
    for (int mi = 0; mi < 4; ++mi)
      afo[ks][mi] = (wm * 64 + mi * 16 + lane15) * 64 + (((ks * 4 + quad) ^ xm) << 3);
#pragma unroll
    for (int ni = 0; ni < 2; ++ni)
      bfo[ks][ni] = (wn * 32 + ni * 16 + lane15) * 64 + (((ks * 4 + quad) ^ xm) << 3);
  }

  floatx4 acc[4][2] = {};

  auto stage = [&](int kt, int buf) {
#pragma unroll
    for (int j = 0; j < 4; ++j)
      gld16(ag[j] + kt, &As[buf * 8192 + (t + j * 256) * 8]);
#pragma unroll
    for (int j = 0; j < 2; ++j)
      gld16(bg[j] + kt, &Bs[buf * 4096 + (t + j * 256) * 8]);
  };
  auto compute = [&](int buf) {
#pragma unroll
    for (int ks = 0; ks < 2; ++ks) {
      short8 af[4], bf[2];
#pragma unroll
      for (int mi = 0; mi < 4; ++mi)
        af[mi] = *(const short8*)&As[buf * 8192 + afo[ks][mi]];
#pragma unroll
      for (int ni = 0; ni < 2; ++ni)
        bf[ni] = *(const short8*)&Bs[buf * 4096 + bfo[ks][ni]];
#pragma unroll
      for (int mi = 0; mi < 4; ++mi)
#pragma unroll
        for (int ni = 0; ni < 2; ++ni)
          acc[mi][ni] = __builtin_amdgcn_mfma_f32_16x16x32_bf16(af[mi], bf[ni],
                                                                acc[mi][ni], 0, 0, 0);
    }
  };

  stage(0, 0);
  __syncthreads();
  for (int kt = 0; kt < 1024; kt += 128) {
    if (kt + 64 < 1024) stage(kt + 64, 1);
    compute(0);
    __syncthreads();
    if (kt + 128 < 1024) stage(kt + 128, 0);
    compute(1);
    __syncthreads();
  }

#pragma unroll
  for (int mi = 0; mi < 4; ++mi)
#pragma unroll
    for (int ni = 0; ni < 2; ++ni) {
      int col = bn + wn * 32 + ni * 16 + lane15;
#pragma unroll
      for (int r = 0; r < 4; ++r) {
        int row = bm + wm * 64 + mi * 16 + quad * 4 + r;
        C[(size_t)row * 1024 + col] = acc[mi][ni][r];
      }
    }
}

// ---------------- flash attention (S^T layout, BM=128, 8 waves, dbuf x2) ----
// Q pre-scaled by 0.125*log2e; p = exp2(s); l via ones-MFMA (C-layout).
__global__ __launch_bounds__(512) void attn_kern(const u16* __restrict__ Q,
                                                 const u16* __restrict__ KP,
                                                 const u16* __restrict__ VT,
                                                 u16* __restrict__ Y) {
  __shared__ __align__(16) u16 Ks[2 * 4096];    // [buf][t'][d], chunk^=(t'&7)
  __shared__ __align__(16) u16 VTs[2 * 4096];   // [buf][d][t'], chunk^=(d&7)
  __shared__ __align__(16) u16 Ps[8192];        // [m 0..127][t'], chunk^=(m&7)
  const int t = threadIdx.x, w = t >> 6, l = t & 63;
  const int lane15 = l & 15, quad = l >> 4;
  const int bh = blockIdx.y, b = bh >> 4, h = bh & 15;
  const int qrow0 = b * 2048 + blockIdx.x * 128;
  const int xm = lane15 & 7;

  short8 qf[2];
#pragma unroll
  for (int ks = 0; ks < 2; ++ks)
    qf[ks] = *(const short8*)&Q[(size_t)(qrow0 + w * 16 + lane15) * 1024 +
                                h * 64 + ks * 32 + quad * 8];

  const short8 vones = {0x3F80, 0x3F80, 0x3F80, 0x3F80,
                        0x3F80, 0x3F80, 0x3F80, 0x3F80};

  floatx4 yacc[4] = {};
  floatx4 lacc = {};

  const int srow = t >> 3;                          // 0..63
  const int scol = (((t & 7) ^ (srow & 7)) << 3);
  const u16* kg = KP + (size_t)(b * 2048 + srow) * 1024 + h * 64 + scol;
  const u16* vg = VT + (size_t)(bh * 64 + srow) * 2048 + scol;

  const int prow = (w * 16 + lane15) * 64;
  int kfo[2][4], vfo[2][4], pwo[4], pro[2];
#pragma unroll
  for (int ks = 0; ks < 2; ++ks)
#pragma unroll
    for (int ti = 0; ti < 4; ++ti)
      kfo[ks][ti] = (ti * 16 + lane15) * 64 + (((ks * 4 + quad) ^ xm) << 3);
#pragma unroll
  for (int ts = 0; ts < 2; ++ts) {
#pragma unroll
    for (int ni = 0; ni < 4; ++ni)
      vfo[ts][ni] = (ni * 16 + lane15) * 64 + (((ts * 4 + quad) ^ xm) << 3);
    pro[ts] = prow + (((ts * 4 + quad) ^ xm) << 3);
  }
#pragma unroll
  for (int ti = 0; ti < 4; ++ti)
    pwo[ti] = prow + (((ti * 2 + (quad >> 1)) ^ xm) << 3) + ((quad & 1) << 2);

  auto stage = [&](int t0n, int buf) {
    gld16(kg + (size_t)t0n * 1024, &Ks[buf + t * 8]);
    gld16(vg + t0n, &VTs[buf + t * 8]);
  };
  auto compute = [&](int buf) {
    floatx4 sacc[4] = {};
#pragma unroll
    for (int ks = 0; ks < 2; ++ks)
#pragma unroll
      for (int ti = 0; ti < 4; ++ti) {
        short8 kf = *(const short8*)&Ks[buf + kfo[ks][ti]];
        sacc[ti] = __builtin_amdgcn_mfma_f32_16x16x32_bf16(kf, qf[ks], sacc[ti], 0, 0, 0);
      }
#pragma unroll
    for (int ti = 0; ti < 4; ++ti) {
      float p0 = fast_exp2(sacc[ti][0]);
      float p1 = fast_exp2(sacc[ti][1]);
      float p2 = fast_exp2(sacc[ti][2]);
      float p3 = fast_exp2(sacc[ti][3]);
      uint2 pk;
      pk.x = pack_bf2(p0, p1);
      pk.y = pack_bf2(p2, p3);
      *(uint2*)&Ps[pwo[ti]] = pk;
    }
#pragma unroll
    for (int ts = 0; ts < 2; ++ts) {
      short8 pf = *(const short8*)&Ps[pro[ts]];
      lacc = __builtin_amdgcn_mfma_f32_16x16x32_bf16(pf, vones, lacc, 0, 0, 0);
#pragma unroll
      for (int ni = 0; ni < 4; ++ni) {
        short8 vf = *(const short8*)&VTs[buf + vfo[ts][ni]];
        yacc[ni] = __builtin_amdgcn_mfma_f32_16x16x32_bf16(pf, vf, yacc[ni], 0, 0, 0);
      }
    }
  };

  stage(0, 0);
  __syncthreads();
  for (int t0 = 0; t0 < 2048; t0 += 128) {
    if (t0 + 64 < 2048) stage(t0 + 64, 4096);
    compute(0);
    __syncthreads();
    if (t0 + 128 < 2048) stage(t0 + 128, 0);
    compute(4096);
    __syncthreads();
  }

#pragma unroll
  for (int r = 0; r < 4; ++r) {
    float linv = 1.0f / lacc[r];
    int row = qrow0 + w * 16 + quad * 4 + r;
#pragma unroll
    for (int ni = 0; ni < 4; ++ni)
      Y[(size_t)row * 1024 + h * 64 + ni * 16 + lane15] = f2bf(yacc[ni][r] * linv);
  }
}

// ---------------- launch ----------------
extern "C" void kernel_launch(void* const* d_in, const int* in_sizes, int n_in,
                              void* d_out, int out_size, void* d_ws, size_t ws_size,
                              hipStream_t stream) {
  const float* query = (const float*)d_in[0];      // [2,2048,1024]
  const float* key_value = (const float*)d_in[1];  // [2,2048,1024]
  const float* Wq = (const float*)d_in[2];         // [1024,1024]
  const float* Wkv = (const float*)d_in[3];        // [1024,2048]
  const float* Wc = (const float*)d_in[4];         // [1024,1024]
  float* out = (float*)d_out;                      // [2,2048,1024] fp32

  const size_t MB = 1024 * 1024;
  char* ws = (char*)d_ws;
  u16* qin  = (u16*)(ws + 0 * MB);    // 8 MB   X bf16
  u16* kvin = (u16*)(ws + 8 * MB);    // 8 MB   KV bf16
  u16* Wqt  = (u16*)(ws + 16 * MB);   // 2 MB
  u16* Wkvt = (u16*)(ws + 18 * MB);   // 4 MB
  u16* Wct  = (u16*)(ws + 22 * MB);   // 2 MB
  u16* qp   = (u16*)(ws + 24 * MB);   // 8 MB   q = X Wq * 0.125*log2e
  u16* kp   = (u16*)(ws + 32 * MB);   // 8 MB   k [4096][1024]
  u16* vt   = (u16*)(ws + 40 * MB);   // 8 MB   v transposed [b*1024+wc][2048]
  u16* y    = (u16*)(ws + 48 * MB);   // 8 MB   attention output

  const int nAct4 = 2 * 2048 * 1024 / 4;
  cvt_bf16_2<<<dim3(nAct4 / 256, 2), dim3(256), 0, stream>>>(query, key_value,
                                                             qin, kvin, nAct4);
  transpose_cvt3<<<dim3(64, 32, 3), dim3(32, 8), 0, stream>>>(Wq, Wkv, Wc,
                                                              Wqt, Wkvt, Wct);
  const float qscale = 0.125f * 1.4426950408889634f;  // 1/sqrt(hd) * log2(e)
  gemm_qkv<<<dim3(24, 32), dim3(256), 0, stream>>>(qin, kvin, Wqt, Wkvt,
                                                   qp, kp, vt, qscale);
  attn_kern<<<dim3(16, 32), dim3(512), 0, stream>>>(qp, kp, vt, y);
  gemm_out<<<dim3(16, 32), dim3(256), 0, stream>>>(y, Wct, out);
}

// Round 8
// 224.696 us; speedup vs baseline: 1.1656x; 1.0004x over previous
//
#include <hip/hip_runtime.h>
#include <hip/hip_bf16.h>

// CrossAttention: out = softmax((X Wq)(KV Wk)^T / 8) (KV Wv) Wc
// B=2 S=T=2048 H=1024 nh=16 hd=64
// R8: launch_bounds(256,3) on gemm_qkv (VGPR 180 was capping occupancy at 2
//     blocks/CU); full row-bit LDS swizzle f(r)=(r&3)^((r>>2)&3) (old x3
//     swizzle left rows m,m+4 on same banks); gemm_out = gemm_body BK=32 +
//     launch_bounds(256,4); single fused prep kernel. 4-dispatch pipeline.

typedef unsigned short u16;
typedef __attribute__((ext_vector_type(4))) float float4v;
typedef __attribute__((ext_vector_type(4))) unsigned short u16x4;
typedef __attribute__((ext_vector_type(8))) short short8;
typedef __attribute__((ext_vector_type(4))) float floatx4;

__device__ __forceinline__ u16 f2bf(float f) {
  unsigned u = __float_as_uint(f);
  u += 0x7fffu + ((u >> 16) & 1u);   // RNE
  return (u16)(u >> 16);
}

__device__ __forceinline__ float fast_exp2(float x) {
#if __has_builtin(__builtin_amdgcn_exp2f)
  return __builtin_amdgcn_exp2f(x);
#else
  return exp2f(x);
#endif
}

// pack two fp32 -> two bf16 in one u32 (low = a), RNE
__device__ __forceinline__ unsigned pack_bf2(float a, float b) {
#if __has_builtin(__builtin_amdgcn_cvt_pk_bf16_f32)
  auto r = __builtin_amdgcn_cvt_pk_bf16_f32(a, b);
  unsigned u;
  __builtin_memcpy(&u, &r, 4);
  return u;
#else
  unsigned ua = __float_as_uint(a) + 0x7fffu + ((__float_as_uint(a) >> 16) & 1u);
  unsigned ub = __float_as_uint(b) + 0x7fffu + ((__float_as_uint(b) >> 16) & 1u);
  return __builtin_amdgcn_perm(ub, ua, 0x07060302u);
#endif
}

__device__ __forceinline__ void gld16(const void* g, void* l) {
  __builtin_amdgcn_global_load_lds(
      (const __attribute__((address_space(1))) void*)g,
      (__attribute__((address_space(3))) void*)l, 16, 0, 0);
}

// row swizzle for 32-elem (4-chunk) LDS rows: 2-to-1 over same-parity rows
__device__ __forceinline__ int swz4(int r) { return (r & 3) ^ ((r >> 2) & 3); }

// ---------------- prep: activation cvt + weight transposes, one launch ------
// bid 0..4095: cvt X | 4096..8191: cvt KV | 8192..: transpose Wq/Wkv/Wc
__global__ void prep(const float* __restrict__ X, const float* __restrict__ KV,
                     const float* __restrict__ Wq, const float* __restrict__ Wkv,
                     const float* __restrict__ Wc,
                     u16* __restrict__ qin, u16* __restrict__ kvin,
                     u16* __restrict__ Wqt, u16* __restrict__ Wkvt,
                     u16* __restrict__ Wct) {
  __shared__ float tile[32][33];
  const int bid = blockIdx.x, t = threadIdx.x;
  if (bid < 8192) {
    const float* src = bid < 4096 ? X : KV;
    u16* dst = bid < 4096 ? qin : kvin;
    int i = (bid & 4095) * 256 + t;
    float4v v = ((const float4v*)src)[i];
    u16x4 o;
    o.x = f2bf(v.x); o.y = f2bf(v.y); o.z = f2bf(v.z); o.w = f2bf(v.w);
    ((u16x4*)dst)[i] = o;
  } else {
    int r = bid - 8192;
    const float* in;
    u16* out;
    int C, bx, by;
    if (r < 1024)      { in = Wq;  out = Wqt;  C = 1024; bx = r & 31; by = r >> 5; }
    else if (r < 3072) { r -= 1024; in = Wkv; out = Wkvt; C = 2048; bx = r & 63; by = r >> 6; }
    else               { r -= 3072; in = Wc;  out = Wct;  C = 1024; bx = r & 31; by = r >> 5; }
    const int tx = t & 31, ty = t >> 5;   // 32 x 8
#pragma unroll
    for (int i = 0; i < 32; i += 8)
      tile[ty + i][tx] = in[(size_t)(by * 32 + ty + i) * C + bx * 32 + tx];
    __syncthreads();
#pragma unroll
    for (int i = 0; i < 32; i += 8)
      out[(size_t)(bx * 32 + ty + i) * 1024 + by * 32 + tx] = f2bf(tile[tx][ty + i]);
  }
}

// ======= fused q/k/v projection (bf16 A), 128x128, BK=32, dbuf ==============
// bx 0..7: q -> qp (scale qscale); bx 8..15: k -> kp;
// bx 16..23: v via swapped MFMA -> vt[(b*1024+wc)][2048] (direct transpose).
__global__ __launch_bounds__(256, 3) void gemm_qkv(const u16* __restrict__ qin,
                                                   const u16* __restrict__ kvin,
                                                   const u16* __restrict__ Wqt,
                                                   const u16* __restrict__ Wkvt,
                                                   u16* __restrict__ qp,
                                                   u16* __restrict__ kp,
                                                   u16* __restrict__ vt,
                                                   float qscale) {
  __shared__ __align__(16) u16 As[2 * 4096];
  __shared__ __align__(16) u16 Bs[2 * 4096];
  const int t = threadIdx.x;
  const int w = t >> 6, l = t & 63;
  const int lane15 = l & 15, quad = l >> 4;
  const int wm = w >> 1, wn = w & 1;
  const int bm = blockIdx.y * 128;

  const int bx = blockIdx.x;
  const int mode = bx >> 3;                 // 0=q 1=k 2=v
  const u16* A = (mode == 0) ? qin : kvin;
  const u16* Bt = (mode == 0) ? Wqt : Wkvt;
  const int bn = (mode == 2) ? 1024 + (bx - 16) * 128 : (bx & 7) * 128;

  const int srow = t >> 2;                            // 0..63
  const int scol = (((t & 3) ^ swz4(srow)) << 3);
  const u16* ag0 = A + (size_t)(bm + srow) * 1024 + scol;
  const u16* ag1 = ag0 + (size_t)64 * 1024;
  const u16* bg0 = Bt + (size_t)(bn + srow) * 1024 + scol;
  const u16* bg1 = bg0 + (size_t)64 * 1024;

  int afo[4], bfo[4];
#pragma unroll
  for (int mi = 0; mi < 4; ++mi) {
    int row = wm * 64 + mi * 16 + lane15;
    afo[mi] = row * 32 + ((quad ^ swz4(row)) << 3);
  }
#pragma unroll
  for (int ni = 0; ni < 4; ++ni) {
    int row = wn * 64 + ni * 16 + lane15;
    bfo[ni] = row * 32 + ((quad ^ swz4(row)) << 3);
  }

  floatx4 acc[4][4] = {};
  const bool vswap = (mode == 2);

  auto stage = [&](int kt, int buf) {
    gld16(ag0 + kt, &As[buf * 4096 + t * 8]);
    gld16(ag1 + kt, &As[buf * 4096 + 2048 + t * 8]);
    gld16(bg0 + kt, &Bs[buf * 4096 + t * 8]);
    gld16(bg1 + kt, &Bs[buf * 4096 + 2048 + t * 8]);
  };
  auto compute = [&](int buf) {
    short8 af[4], bf[4];
#pragma unroll
    for (int mi = 0; mi < 4; ++mi) af[mi] = *(const short8*)&As[buf * 4096 + afo[mi]];
#pragma unroll
    for (int ni = 0; ni < 4; ++ni) bf[ni] = *(const short8*)&Bs[buf * 4096 + bfo[ni]];
    if (!vswap) {
#pragma unroll
      for (int mi = 0; mi < 4; ++mi)
#pragma unroll
        for (int ni = 0; ni < 4; ++ni)
          acc[mi][ni] = __builtin_amdgcn_mfma_f32_16x16x32_bf16(af[mi], bf[ni],
                                                                acc[mi][ni], 0, 0, 0);
    } else {
#pragma unroll
      for (int mi = 0; mi < 4; ++mi)
#pragma unroll
        for (int ni = 0; ni < 4; ++ni)
          acc[mi][ni] = __builtin_amdgcn_mfma_f32_16x16x32_bf16(bf[ni], af[mi],
                                                                acc[mi][ni], 0, 0, 0);
    }
  };

  stage(0, 0);
  __syncthreads();
  for (int kt = 0; kt < 1024; kt += 64) {
    if (kt + 32 < 1024) stage(kt + 32, 1);
    compute(0);
    __syncthreads();
    if (kt + 64 < 1024) stage(kt + 64, 0);
    compute(1);
    __syncthreads();
  }

  if (mode == 0) {
#pragma unroll
    for (int mi = 0; mi < 4; ++mi)
#pragma unroll
      for (int ni = 0; ni < 4; ++ni) {
        int col = bn + wn * 64 + ni * 16 + lane15;
#pragma unroll
        for (int r = 0; r < 4; ++r) {
          int row = bm + wm * 64 + mi * 16 + quad * 4 + r;
          qp[(size_t)row * 1024 + col] = f2bf(acc[mi][ni][r] * qscale);
        }
      }
  } else if (mode == 1) {
#pragma unroll
    for (int mi = 0; mi < 4; ++mi)
#pragma unroll
      for (int ni = 0; ni < 4; ++ni) {
        int col = bn + wn * 64 + ni * 16 + lane15;
#pragma unroll
        for (int r = 0; r < 4; ++r) {
          int row = bm + wm * 64 + mi * 16 + quad * 4 + r;
          kp[(size_t)row * 1024 + col] = f2bf(acc[mi][ni][r]);
        }
      }
  } else {
    // swapped: D rows = weight col (wc), D cols = activation row (t)
    const int b = bm >> 11;
    const int tbase = (bm & 2047) + wm * 64;
#pragma unroll
    for (int mi = 0; mi < 4; ++mi)
#pragma unroll
      for (int ni = 0; ni < 4; ++ni) {
        int tloc = tbase + mi * 16 + lane15;
#pragma unroll
        for (int r = 0; r < 4; ++r) {
          int wc = (bn - 1024) + wn * 64 + ni * 16 + quad * 4 + r;
          vt[(size_t)(b * 1024 + wc) * 2048 + tloc] = f2bf(acc[mi][ni][r]);
        }
      }
  }
}

// ================ GEMM body (bf16): 128 x (NI*32) tile, BK=32, dbuf ==========
template <typename OutT, int NI>
__device__ __forceinline__ void gemm_body(const u16* __restrict__ A,
                                          const u16* __restrict__ Bt,
                                          OutT* __restrict__ C,
                                          int N, int lda, int Klen, float scale,
                                          int bm, int bn,
                                          u16* As, u16* Bs) {
  const int t = threadIdx.x;
  const int w = t >> 6, l = t & 63;
  const int lane15 = l & 15, quad = l >> 4;
  const int wm = w >> 1, wn = w & 1;
  const int BSZ = NI * 1024;

  const int srow = t >> 2;
  const int scol = (((t & 3) ^ swz4(srow)) << 3);
  const u16* ag0 = A + (size_t)(bm + srow) * lda + scol;
  const u16* ag1 = ag0 + (size_t)64 * lda;
  const u16* bg0 = Bt + (size_t)(bn + srow) * lda + scol;
  const u16* bg1 = bg0 + (size_t)64 * lda;

  int afo[4], bfo[NI];
#pragma unroll
  for (int mi = 0; mi < 4; ++mi) {
    int row = wm * 64 + mi * 16 + lane15;
    afo[mi] = row * 32 + ((quad ^ swz4(row)) << 3);
  }
#pragma unroll
  for (int ni = 0; ni < NI; ++ni) {
    int row = wn * (NI * 16) + ni * 16 + lane15;
    bfo[ni] = row * 32 + ((quad ^ swz4(row)) << 3);
  }

  floatx4 acc[4][NI] = {};

  auto stage = [&](int kt, int ab, int bb) {
    gld16(ag0 + kt, &As[ab + t * 8]);
    gld16(ag1 + kt, &As[ab + 2048 + t * 8]);
    gld16(bg0 + kt, &Bs[bb + t * 8]);
    if (NI == 4) gld16(bg1 + kt, &Bs[bb + 2048 + t * 8]);
  };
  auto compute = [&](int ab, int bb) {
    short8 af[4], bf[NI];
#pragma unroll
    for (int mi = 0; mi < 4; ++mi) af[mi] = *(const short8*)&As[ab + afo[mi]];
#pragma unroll
    for (int ni = 0; ni < NI; ++ni) bf[ni] = *(const short8*)&Bs[bb + bfo[ni]];
#pragma unroll
    for (int mi = 0; mi < 4; ++mi)
#pragma unroll
      for (int ni = 0; ni < NI; ++ni)
        acc[mi][ni] = __builtin_amdgcn_mfma_f32_16x16x32_bf16(af[mi], bf[ni],
                                                              acc[mi][ni], 0, 0, 0);
  };

  stage(0, 0, 0);
  __syncthreads();
  for (int kt = 0; kt < Klen; kt += 64) {
    if (kt + 32 < Klen) stage(kt + 32, 4096, BSZ);
    compute(0, 0);
    __syncthreads();
    if (kt + 64 < Klen) stage(kt + 64, 0, 0);
    compute(4096, BSZ);
    __syncthreads();
  }

#pragma unroll
  for (int mi = 0; mi < 4; ++mi)
#pragma unroll
    for (int ni = 0; ni < NI; ++ni) {
      int col = bn + wn * (NI * 16) + ni * 16 + lane15;
#pragma unroll
      for (int r = 0; r < 4; ++r) {
        int row = bm + wm * 64 + mi * 16 + quad * 4 + r;
        if constexpr (sizeof(OutT) == 4)
          C[(size_t)row * N + col] = acc[mi][ni][r] * scale;
        else
          C[(size_t)row * N + col] = f2bf(acc[mi][ni][r] * scale);
      }
    }
}

// output projection, 128x64 tiles (512 blocks), 24 KB LDS, 4 blocks/CU
__global__ __launch_bounds__(256, 4) void gemm_out(const u16* __restrict__ A,
                                                   const u16* __restrict__ Bt,
                                                   float* __restrict__ C) {
  __shared__ __align__(16) u16 As[2 * 4096];
  __shared__ __align__(16) u16 Bs[2 * 2048];
  gemm_body<float, 2>(A, Bt, C, 1024, 1024, 1024, 1.0f, blockIdx.y * 128,
                      blockIdx.x * 64, As, Bs);
}

// ---------------- flash attention (S^T layout, BM=128, 8 waves, dbuf x2) ----
// Q pre-scaled by 0.125*log2e; p = exp2(s); l via ones-MFMA (C-layout).
__global__ __launch_bounds__(512) void attn_kern(const u16* __restrict__ Q,
                                                 const u16* __restrict__ KP,
                                                 const u16* __restrict__ VT,
                                                 u16* __restrict__ Y) {
  __shared__ __align__(16) u16 Ks[2 * 4096];    // [buf][t'][d], chunk^=(t'&7)
  __shared__ __align__(16) u16 VTs[2 * 4096];   // [buf][d][t'], chunk^=(d&7)
  __shared__ __align__(16) u16 Ps[8192];        // [m 0..127][t'], chunk^=(m&7)
  const int t = threadIdx.x, w = t >> 6, l = t & 63;
  const int lane15 = l & 15, quad = l >> 4;
  const int bh = blockIdx.y, b = bh >> 4, h = bh & 15;
  const int qrow0 = b * 2048 + blockIdx.x * 128;
  const int xm = lane15 & 7;

  short8 qf[2];
#pragma unroll
  for (int ks = 0; ks < 2; ++ks)
    qf[ks] = *(const short8*)&Q[(size_t)(qrow0 + w * 16 + lane15) * 1024 +
                                h * 64 + ks * 32 + quad * 8];

  const short8 vones = {0x3F80, 0x3F80, 0x3F80, 0x3F80,
                        0x3F80, 0x3F80, 0x3F80, 0x3F80};

  floatx4 yacc[4] = {};
  floatx4 lacc = {};

  const int srow = t >> 3;                          // 0..63
  const int scol = (((t & 7) ^ (srow & 7)) << 3);
  const u16* kg = KP + (size_t)(b * 2048 + srow) * 1024 + h * 64 + scol;
  const u16* vg = VT + (size_t)(bh * 64 + srow) * 2048 + scol;

  const int prow = (w * 16 + lane15) * 64;
  int kfo[2][4], vfo[2][4], pwo[4], pro[2];
#pragma unroll
  for (int ks = 0; ks < 2; ++ks)
#pragma unroll
    for (int ti = 0; ti < 4; ++ti)
      kfo[ks][ti] = (ti * 16 + lane15) * 64 + (((ks * 4 + quad) ^ xm) << 3);
#pragma unroll
  for (int ts = 0; ts < 2; ++ts) {
#pragma unroll
    for (int ni = 0; ni < 4; ++ni)
      vfo[ts][ni] = (ni * 16 + lane15) * 64 + (((ts * 4 + quad) ^ xm) << 3);
    pro[ts] = prow + (((ts * 4 + quad) ^ xm) << 3);
  }
#pragma unroll
  for (int ti = 0; ti < 4; ++ti)
    pwo[ti] = prow + (((ti * 2 + (quad >> 1)) ^ xm) << 3) + ((quad & 1) << 2);

  auto stage = [&](int t0n, int buf) {
    gld16(kg + (size_t)t0n * 1024, &Ks[buf + t * 8]);
    gld16(vg + t0n, &VTs[buf + t * 8]);
  };
  auto compute = [&](int buf) {
    floatx4 sacc[4] = {};
#pragma unroll
    for (int ks = 0; ks < 2; ++ks)
#pragma unroll
      for (int ti = 0; ti < 4; ++ti) {
        short8 kf = *(const short8*)&Ks[buf + kfo[ks][ti]];
        sacc[ti] = __builtin_amdgcn_mfma_f32_16x16x32_bf16(kf, qf[ks], sacc[ti], 0, 0, 0);
      }
#pragma unroll
    for (int ti = 0; ti < 4; ++ti) {
      float p0 = fast_exp2(sacc[ti][0]);
      float p1 = fast_exp2(sacc[ti][1]);
      float p2 = fast_exp2(sacc[ti][2]);
      float p3 = fast_exp2(sacc[ti][3]);
      uint2 pk;
      pk.x = pack_bf2(p0, p1);
      pk.y = pack_bf2(p2, p3);
      *(uint2*)&Ps[pwo[ti]] = pk;
    }
#pragma unroll
    for (int ts = 0; ts < 2; ++ts) {
      short8 pf = *(const short8*)&Ps[pro[ts]];
      lacc = __builtin_amdgcn_mfma_f32_16x16x32_bf16(pf, vones, lacc, 0, 0, 0);
#pragma unroll
      for (int ni = 0; ni < 4; ++ni) {
        short8 vf = *(const short8*)&VTs[buf + vfo[ts][ni]];
        yacc[ni] = __builtin_amdgcn_mfma_f32_16x16x32_bf16(pf, vf, yacc[ni], 0, 0, 0);
      }
    }
  };

  stage(0, 0);
  __syncthreads();
  for (int t0 = 0; t0 < 2048; t0 += 128) {
    if (t0 + 64 < 2048) stage(t0 + 64, 4096);
    compute(0);
    __syncthreads();
    if (t0 + 128 < 2048) stage(t0 + 128, 0);
    compute(4096);
    __syncthreads();
  }

#pragma unroll
  for (int r = 0; r < 4; ++r) {
    float linv = 1.0f / lacc[r];
    int row = qrow0 + w * 16 + quad * 4 + r;
#pragma unroll
    for (int ni = 0; ni < 4; ++ni)
      Y[(size_t)row * 1024 + h * 64 + ni * 16 + lane15] = f2bf(yacc[ni][r] * linv);
  }
}

// ---------------- launch ----------------
extern "C" void kernel_launch(void* const* d_in, const int* in_sizes, int n_in,
                              void* d_out, int out_size, void* d_ws, size_t ws_size,
                              hipStream_t stream) {
  const float* query = (const float*)d_in[0];      // [2,2048,1024]
  const float* key_value = (const float*)d_in[1];  // [2,2048,1024]
  const float* Wq = (const float*)d_in[2];         // [1024,1024]
  const float* Wkv = (const float*)d_in[3];        // [1024,2048]
  const float* Wc = (const float*)d_in[4];         // [1024,1024]
  float* out = (float*)d_out;                      // [2,2048,1024] fp32

  const size_t MB = 1024 * 1024;
  char* ws = (char*)d_ws;
  u16* qin  = (u16*)(ws + 0 * MB);    // 8 MB   X bf16
  u16* kvin = (u16*)(ws + 8 * MB);    // 8 MB   KV bf16
  u16* Wqt  = (u16*)(ws + 16 * MB);   // 2 MB
  u16* Wkvt = (u16*)(ws + 18 * MB);   // 4 MB
  u16* Wct  = (u16*)(ws + 22 * MB);   // 2 MB
  u16* qp   = (u16*)(ws + 24 * MB);   // 8 MB   q = X Wq * 0.125*log2e
  u16* kp   = (u16*)(ws + 32 * MB);   // 8 MB   k [4096][1024]
  u16* vt   = (u16*)(ws + 40 * MB);   // 8 MB   v transposed [b*1024+wc][2048]
  u16* y    = (u16*)(ws + 48 * MB);   // 8 MB   attention output

  prep<<<dim3(12288), dim3(256), 0, stream>>>(query, key_value, Wq, Wkv, Wc,
                                              qin, kvin, Wqt, Wkvt, Wct);
  const float qscale = 0.125f * 1.4426950408889634f;  // 1/sqrt(hd) * log2(e)
  gemm_qkv<<<dim3(24, 32), dim3(256), 0, stream>>>(qin, kvin, Wqt, Wkvt,
                                                   qp, kp, vt, qscale);
  attn_kern<<<dim3(16, 32), dim3(512), 0, stream>>>(qp, kp, vt, y);
  gemm_out<<<dim3(16, 32), dim3(256), 0, stream>>>(y, Wct, out);
}

// Round 9
// 209.346 us; speedup vs baseline: 1.2511x; 1.0733x over previous
//
#include <hip/hip_runtime.h>
#include <hip/hip_bf16.h>

// CrossAttention: out = softmax((X Wq)(KV Wk)^T / 8) (KV Wv) Wc
// B=2 S=T=2048 H=1024 nh=16 hd=64
// R9: L2-traffic attack. (1) LDS-repacked epilogues -> full-line 16B/lane
//     stores (R8 WRITE_SIZE was 110 MB vs 24 logical: 32B fragments evicted
//     partial). (2) XCD-aware block swizzle (bid%8=XCD): compact per-XCD tile
//     patches -> per-XCD working set ~5MB vs whole-problem.

typedef unsigned short u16;
typedef __attribute__((ext_vector_type(4))) float float4v;
typedef __attribute__((ext_vector_type(4))) unsigned short u16x4;
typedef __attribute__((ext_vector_type(8))) short short8;
typedef __attribute__((ext_vector_type(4))) float floatx4;

__device__ __forceinline__ u16 f2bf(float f) {
  unsigned u = __float_as_uint(f);
  u += 0x7fffu + ((u >> 16) & 1u);   // RNE
  return (u16)(u >> 16);
}

__device__ __forceinline__ float fast_exp2(float x) {
#if __has_builtin(__builtin_amdgcn_exp2f)
  return __builtin_amdgcn_exp2f(x);
#else
  return exp2f(x);
#endif
}

__device__ __forceinline__ unsigned pack_bf2(float a, float b) {
#if __has_builtin(__builtin_amdgcn_cvt_pk_bf16_f32)
  auto r = __builtin_amdgcn_cvt_pk_bf16_f32(a, b);
  unsigned u;
  __builtin_memcpy(&u, &r, 4);
  return u;
#else
  unsigned ua = __float_as_uint(a) + 0x7fffu + ((__float_as_uint(a) >> 16) & 1u);
  unsigned ub = __float_as_uint(b) + 0x7fffu + ((__float_as_uint(b) >> 16) & 1u);
  return __builtin_amdgcn_perm(ub, ua, 0x07060302u);
#endif
}

__device__ __forceinline__ void gld16(const void* g, void* l) {
  __builtin_amdgcn_global_load_lds(
      (const __attribute__((address_space(1))) void*)g,
      (__attribute__((address_space(3))) void*)l, 16, 0, 0);
}

// row swizzle for 32-elem (4-chunk) LDS rows
__device__ __forceinline__ int swz4(int r) { return (r & 3) ^ ((r >> 2) & 3); }

// ---------------- prep: activation cvt + weight transposes, one launch ------
__global__ void prep(const float* __restrict__ X, const float* __restrict__ KV,
                     const float* __restrict__ Wq, const float* __restrict__ Wkv,
                     const float* __restrict__ Wc,
                     u16* __restrict__ qin, u16* __restrict__ kvin,
                     u16* __restrict__ Wqt, u16* __restrict__ Wkvt,
                     u16* __restrict__ Wct) {
  __shared__ float tile[32][33];
  const int bid = blockIdx.x, t = threadIdx.x;
  if (bid < 8192) {
    const float* src = bid < 4096 ? X : KV;
    u16* dst = bid < 4096 ? qin : kvin;
    int i = (bid & 4095) * 256 + t;
    float4v v = ((const float4v*)src)[i];
    u16x4 o;
    o.x = f2bf(v.x); o.y = f2bf(v.y); o.z = f2bf(v.z); o.w = f2bf(v.w);
    ((u16x4*)dst)[i] = o;
  } else {
    int r = bid - 8192;
    const float* in;
    u16* out;
    int C, bx, by;
    if (r < 1024)      { in = Wq;  out = Wqt;  C = 1024; bx = r & 31; by = r >> 5; }
    else if (r < 3072) { r -= 1024; in = Wkv; out = Wkvt; C = 2048; bx = r & 63; by = r >> 6; }
    else               { r -= 3072; in = Wc;  out = Wct;  C = 1024; bx = r & 31; by = r >> 5; }
    const int tx = t & 31, ty = t >> 5;   // 32 x 8
#pragma unroll
    for (int i = 0; i < 32; i += 8)
      tile[ty + i][tx] = in[(size_t)(by * 32 + ty + i) * C + bx * 32 + tx];
    __syncthreads();
#pragma unroll
    for (int i = 0; i < 32; i += 8)
      out[(size_t)(bx * 32 + ty + i) * 1024 + by * 32 + tx] = f2bf(tile[tx][ty + i]);
  }
}

// ======= fused q/k/v projection (bf16), 128x128, BK=32, dbuf ================
// 1D grid 768; XCD patch swizzle. bx 0..7: q; 8..15: k; 16..23: v (swapped
// MFMA -> vt direct transpose). LDS-repacked full-line epilogues.
__global__ __launch_bounds__(256, 3) void gemm_qkv(const u16* __restrict__ qin,
                                                   const u16* __restrict__ kvin,
                                                   const u16* __restrict__ Wqt,
                                                   const u16* __restrict__ Wkvt,
                                                   u16* __restrict__ qp,
                                                   u16* __restrict__ kp,
                                                   u16* __restrict__ vt,
                                                   float qscale) {
  __shared__ __align__(16) u16 Shm[16384];   // 32 KB: As | Bs, epilogue tile
  u16* As = Shm;
  u16* Bs = Shm + 8192;
  const int t = threadIdx.x;
  const int w = t >> 6, l = t & 63;
  const int lane15 = l & 15, quad = l >> 4;
  const int wm = w >> 1, wn = w & 1;

  // XCD patch swizzle: XCD r gets bx in [12*(r&1),+12), by in [8*(r>>1),+8)
  const int bid = blockIdx.x;
  const int xr = bid & 7, g = bid >> 3;          // g in [0,96)
  const int bx = 12 * (xr & 1) + g % 12;
  const int by = 8 * (xr >> 1) + g / 12;
  const int bm = by * 128;

  const int mode = bx >> 3;                 // 0=q 1=k 2=v
  const u16* A = (mode == 0) ? qin : kvin;
  const u16* Bt = (mode == 0) ? Wqt : Wkvt;
  const int bn = (mode == 2) ? 1024 + (bx - 16) * 128 : (bx & 7) * 128;

  const int srow = t >> 2;                            // 0..63
  const int scol = (((t & 3) ^ swz4(srow)) << 3);
  const u16* ag0 = A + (size_t)(bm + srow) * 1024 + scol;
  const u16* ag1 = ag0 + (size_t)64 * 1024;
  const u16* bg0 = Bt + (size_t)(bn + srow) * 1024 + scol;
  const u16* bg1 = bg0 + (size_t)64 * 1024;

  int afo[4], bfo[4];
#pragma unroll
  for (int mi = 0; mi < 4; ++mi) {
    int row = wm * 64 + mi * 16 + lane15;
    afo[mi] = row * 32 + ((quad ^ swz4(row)) << 3);
  }
#pragma unroll
  for (int ni = 0; ni < 4; ++ni) {
    int row = wn * 64 + ni * 16 + lane15;
    bfo[ni] = row * 32 + ((quad ^ swz4(row)) << 3);
  }

  floatx4 acc[4][4] = {};
  const bool vswap = (mode == 2);

  auto stage = [&](int kt, int buf) {
    gld16(ag0 + kt, &As[buf * 4096 + t * 8]);
    gld16(ag1 + kt, &As[buf * 4096 + 2048 + t * 8]);
    gld16(bg0 + kt, &Bs[buf * 4096 + t * 8]);
    gld16(bg1 + kt, &Bs[buf * 4096 + 2048 + t * 8]);
  };
  auto compute = [&](int buf) {
    short8 af[4], bf[4];
#pragma unroll
    for (int mi = 0; mi < 4; ++mi) af[mi] = *(const short8*)&As[buf * 4096 + afo[mi]];
#pragma unroll
    for (int ni = 0; ni < 4; ++ni) bf[ni] = *(const short8*)&Bs[buf * 4096 + bfo[ni]];
    if (!vswap) {
#pragma unroll
      for (int mi = 0; mi < 4; ++mi)
#pragma unroll
        for (int ni = 0; ni < 4; ++ni)
          acc[mi][ni] = __builtin_amdgcn_mfma_f32_16x16x32_bf16(af[mi], bf[ni],
                                                                acc[mi][ni], 0, 0, 0);
    } else {
#pragma unroll
      for (int mi = 0; mi < 4; ++mi)
#pragma unroll
        for (int ni = 0; ni < 4; ++ni)
          acc[mi][ni] = __builtin_amdgcn_mfma_f32_16x16x32_bf16(bf[ni], af[mi],
                                                                acc[mi][ni], 0, 0, 0);
    }
  };

  stage(0, 0);
  __syncthreads();
  for (int kt = 0; kt < 1024; kt += 64) {
    if (kt + 32 < 1024) stage(kt + 32, 1);
    compute(0);
    __syncthreads();
    if (kt + 64 < 1024) stage(kt + 64, 0);
    compute(1);
    __syncthreads();
  }

  // ---- LDS-repacked epilogue: scatter C-layout -> Shm, linear 16B stores ---
  const float scale = (mode == 0) ? qscale : 1.0f;
  __syncthreads();   // LDS free
#pragma unroll
  for (int mi = 0; mi < 4; ++mi)
#pragma unroll
    for (int ni = 0; ni < 4; ++ni)
#pragma unroll
      for (int r = 0; r < 4; ++r) {
        int rl, cl;
        if (!vswap) {   // rows = m, cols = n
          rl = wm * 64 + mi * 16 + quad * 4 + r;
          cl = wn * 64 + ni * 16 + lane15;
        } else {        // rows = weight-col, cols = activation row (t)
          rl = wn * 64 + ni * 16 + quad * 4 + r;
          cl = wm * 64 + mi * 16 + lane15;
        }
        Shm[rl * 128 + (cl ^ ((rl & 3) << 4))] = f2bf(acc[mi][ni][r] * scale);
      }
  __syncthreads();
#pragma unroll
  for (int j = 0; j < 8; ++j) {
    int c = t + j * 256;             // 2048 chunks of 8 u16
    int row = c >> 4, ch = c & 15;
    short8 v = *(const short8*)&Shm[row * 128 + ((ch ^ ((row & 3) << 1)) << 3)];
    if (mode == 0)
      *(short8*)&qp[(size_t)(bm + row) * 1024 + bn + ch * 8] = v;
    else if (mode == 1)
      *(short8*)&kp[(size_t)(bm + row) * 1024 + bn + ch * 8] = v;
    else {
      int b = bm >> 11;
      *(short8*)&vt[(size_t)(b * 1024 + (bn - 1024) + row) * 2048 +
                    (bm & 2047) + ch * 8] = v;
    }
  }
}

// ============== output projection: 128x64, BK=32, dbuf, repacked fp32 =======
__global__ __launch_bounds__(256, 4) void gemm_out(const u16* __restrict__ A,
                                                   const u16* __restrict__ Bt,
                                                   float* __restrict__ C) {
  __shared__ __align__(16) u16 Shm[16384];   // 32 KB; loop uses 24, epi 32
  u16* As = Shm;                             // 2*4096
  u16* Bs = Shm + 8192;                      // 2*2048
  float* Shf = (float*)Shm;                  // epilogue: [128][64] fp32
  const int t = threadIdx.x;
  const int w = t >> 6, l = t & 63;
  const int lane15 = l & 15, quad = l >> 4;
  const int wm = w >> 1, wn = w & 1;

  const int bid = blockIdx.x;                // 512 blocks
  const int xr = bid & 7, g = bid >> 3;      // g in [0,64)
  const int bx = 8 * (xr & 1) + g % 8;       // [0,16)
  const int by = 8 * (xr >> 1) + g / 8;      // [0,32)
  const int bm = by * 128, bn = bx * 64;

  const int srow = t >> 2;
  const int scol = (((t & 3) ^ swz4(srow)) << 3);
  const u16* ag0 = A + (size_t)(bm + srow) * 1024 + scol;
  const u16* ag1 = ag0 + (size_t)64 * 1024;
  const u16* bg0 = Bt + (size_t)(bn + srow) * 1024 + scol;

  int afo[4], bfo[2];
#pragma unroll
  for (int mi = 0; mi < 4; ++mi) {
    int row = wm * 64 + mi * 16 + lane15;
    afo[mi] = row * 32 + ((quad ^ swz4(row)) << 3);
  }
#pragma unroll
  for (int ni = 0; ni < 2; ++ni) {
    int row = wn * 32 + ni * 16 + lane15;
    bfo[ni] = row * 32 + ((quad ^ swz4(row)) << 3);
  }

  floatx4 acc[4][2] = {};

  auto stage = [&](int kt, int buf) {
    gld16(ag0 + kt, &As[buf * 4096 + t * 8]);
    gld16(ag1 + kt, &As[buf * 4096 + 2048 + t * 8]);
    gld16(bg0 + kt, &Bs[buf * 2048 + t * 8]);
  };
  auto compute = [&](int buf) {
    short8 af[4], bf[2];
#pragma unroll
    for (int mi = 0; mi < 4; ++mi) af[mi] = *(const short8*)&As[buf * 4096 + afo[mi]];
#pragma unroll
    for (int ni = 0; ni < 2; ++ni) bf[ni] = *(const short8*)&Bs[buf * 2048 + bfo[ni]];
#pragma unroll
    for (int mi = 0; mi < 4; ++mi)
#pragma unroll
      for (int ni = 0; ni < 2; ++ni)
        acc[mi][ni] = __builtin_amdgcn_mfma_f32_16x16x32_bf16(af[mi], bf[ni],
                                                              acc[mi][ni], 0, 0, 0);
  };

  stage(0, 0);
  __syncthreads();
  for (int kt = 0; kt < 1024; kt += 64) {
    if (kt + 32 < 1024) stage(kt + 32, 1);
    compute(0);
    __syncthreads();
    if (kt + 64 < 1024) stage(kt + 64, 0);
    compute(1);
    __syncthreads();
  }

  __syncthreads();
#pragma unroll
  for (int mi = 0; mi < 4; ++mi)
#pragma unroll
    for (int ni = 0; ni < 2; ++ni)
#pragma unroll
      for (int r = 0; r < 4; ++r) {
        int rl = wm * 64 + mi * 16 + quad * 4 + r;
        int cl = wn * 32 + ni * 16 + lane15;
        Shf[rl * 64 + (cl ^ ((rl & 3) << 4))] = acc[mi][ni][r];
      }
  __syncthreads();
#pragma unroll
  for (int j = 0; j < 8; ++j) {
    int c = t + j * 256;             // 2048 chunks of float4
    int row = c >> 4, ch = c & 15;
    float4v v = *(const float4v*)&Shf[row * 64 + ((ch ^ ((row & 3) << 2)) << 2)];
    *(float4v*)&C[(size_t)(bm + row) * 1024 + bn + ch * 4] = v;
  }
}

// ---------------- flash attention (S^T layout, BM=128, 8 waves, dbuf x2) ----
__global__ __launch_bounds__(512) void attn_kern(const u16* __restrict__ Q,
                                                 const u16* __restrict__ KP,
                                                 const u16* __restrict__ VT,
                                                 u16* __restrict__ Y) {
  __shared__ __align__(16) u16 Ks[2 * 4096];
  __shared__ __align__(16) u16 VTs[2 * 4096];
  __shared__ __align__(16) u16 Ps[8192];
  const int t = threadIdx.x, w = t >> 6, l = t & 63;
  const int lane15 = l & 15, quad = l >> 4;

  // XCD patch swizzle over (x 16, bh 32)
  const int bid = blockIdx.x;
  const int xr = bid & 7, g = bid >> 3;     // g in [0,64)
  const int bxt = 8 * (xr & 1) + g % 8;     // [0,16)
  const int bh = 8 * (xr >> 1) + g / 8;     // [0,32)
  const int b = bh >> 4, h = bh & 15;
  const int qrow0 = b * 2048 + bxt * 128;
  const int xm = lane15 & 7;

  short8 qf[2];
#pragma unroll
  for (int ks = 0; ks < 2; ++ks)
    qf[ks] = *(const short8*)&Q[(size_t)(qrow0 + w * 16 + lane15) * 1024 +
                                h * 64 + ks * 32 + quad * 8];

  const short8 vones = {0x3F80, 0x3F80, 0x3F80, 0x3F80,
                        0x3F80, 0x3F80, 0x3F80, 0x3F80};

  floatx4 yacc[4] = {};
  floatx4 lacc = {};

  const int srow = t >> 3;                          // 0..63
  const int scol = (((t & 7) ^ (srow & 7)) << 3);
  const u16* kg = KP + (size_t)(b * 2048 + srow) * 1024 + h * 64 + scol;
  const u16* vg = VT + (size_t)(bh * 64 + srow) * 2048 + scol;

  const int prow = (w * 16 + lane15) * 64;
  int kfo[2][4], vfo[2][4], pwo[4], pro[2];
#pragma unroll
  for (int ks = 0; ks < 2; ++ks)
#pragma unroll
    for (int ti = 0; ti < 4; ++ti)
      kfo[ks][ti] = (ti * 16 + lane15) * 64 + (((ks * 4 + quad) ^ xm) << 3);
#pragma unroll
  for (int ts = 0; ts < 2; ++ts) {
#pragma unroll
    for (int ni = 0; ni < 4; ++ni)
      vfo[ts][ni] = (ni * 16 + lane15) * 64 + (((ts * 4 + quad) ^ xm) << 3);
    pro[ts] = prow + (((ts * 4 + quad) ^ xm) << 3);
  }
#pragma unroll
  for (int ti = 0; ti < 4; ++ti)
    pwo[ti] = prow + (((ti * 2 + (quad >> 1)) ^ xm) << 3) + ((quad & 1) << 2);

  auto stage = [&](int t0n, int buf) {
    gld16(kg + (size_t)t0n * 1024, &Ks[buf + t * 8]);
    gld16(vg + t0n, &VTs[buf + t * 8]);
  };
  auto compute = [&](int buf) {
    floatx4 sacc[4] = {};
#pragma unroll
    for (int ks = 0; ks < 2; ++ks)
#pragma unroll
      for (int ti = 0; ti < 4; ++ti) {
        short8 kf = *(const short8*)&Ks[buf + kfo[ks][ti]];
        sacc[ti] = __builtin_amdgcn_mfma_f32_16x16x32_bf16(kf, qf[ks], sacc[ti], 0, 0, 0);
      }
#pragma unroll
    for (int ti = 0; ti < 4; ++ti) {
      float p0 = fast_exp2(sacc[ti][0]);
      float p1 = fast_exp2(sacc[ti][1]);
      float p2 = fast_exp2(sacc[ti][2]);
      float p3 = fast_exp2(sacc[ti][3]);
      uint2 pk;
      pk.x = pack_bf2(p0, p1);
      pk.y = pack_bf2(p2, p3);
      *(uint2*)&Ps[pwo[ti]] = pk;
    }
#pragma unroll
    for (int ts = 0; ts < 2; ++ts) {
      short8 pf = *(const short8*)&Ps[pro[ts]];
      lacc = __builtin_amdgcn_mfma_f32_16x16x32_bf16(pf, vones, lacc, 0, 0, 0);
#pragma unroll
      for (int ni = 0; ni < 4; ++ni) {
        short8 vf = *(const short8*)&VTs[buf + vfo[ts][ni]];
        yacc[ni] = __builtin_amdgcn_mfma_f32_16x16x32_bf16(pf, vf, yacc[ni], 0, 0, 0);
      }
    }
  };

  stage(0, 0);
  __syncthreads();
  for (int t0 = 0; t0 < 2048; t0 += 128) {
    if (t0 + 64 < 2048) stage(t0 + 64, 4096);
    compute(0);
    __syncthreads();
    if (t0 + 128 < 2048) stage(t0 + 128, 0);
    compute(4096);
    __syncthreads();
  }

#pragma unroll
  for (int r = 0; r < 4; ++r) {
    float linv = 1.0f / lacc[r];
    int row = qrow0 + w * 16 + quad * 4 + r;
#pragma unroll
    for (int ni = 0; ni < 4; ++ni)
      Y[(size_t)row * 1024 + h * 64 + ni * 16 + lane15] = f2bf(yacc[ni][r] * linv);
  }
}

// ---------------- launch ----------------
extern "C" void kernel_launch(void* const* d_in, const int* in_sizes, int n_in,
                              void* d_out, int out_size, void* d_ws, size_t ws_size,
                              hipStream_t stream) {
  const float* query = (const float*)d_in[0];
  const float* key_value = (const float*)d_in[1];
  const float* Wq = (const float*)d_in[2];
  const float* Wkv = (const float*)d_in[3];
  const float* Wc = (const float*)d_in[4];
  float* out = (float*)d_out;

  const size_t MB = 1024 * 1024;
  char* ws = (char*)d_ws;
  u16* qin  = (u16*)(ws + 0 * MB);
  u16* kvin = (u16*)(ws + 8 * MB);
  u16* Wqt  = (u16*)(ws + 16 * MB);
  u16* Wkvt = (u16*)(ws + 18 * MB);
  u16* Wct  = (u16*)(ws + 22 * MB);
  u16* qp   = (u16*)(ws + 24 * MB);
  u16* kp   = (u16*)(ws + 32 * MB);
  u16* vt   = (u16*)(ws + 40 * MB);
  u16* y    = (u16*)(ws + 48 * MB);

  prep<<<dim3(12288), dim3(256), 0, stream>>>(query, key_value, Wq, Wkv, Wc,
                                              qin, kvin, Wqt, Wkvt, Wct);
  const float qscale = 0.125f * 1.4426950408889634f;
  gemm_qkv<<<dim3(768), dim3(256), 0, stream>>>(qin, kvin, Wqt, Wkvt,
                                                qp, kp, vt, qscale);
  attn_kern<<<dim3(512), dim3(512), 0, stream>>>(qp, kp, vt, y);
  gemm_out<<<dim3(512), dim3(256), 0, stream>>>(y, Wct, out);
}